// Round 7
// baseline (178.737 us; speedup 1.0000x reference)
//
#include <hip/hip_runtime.h>
#include <hip/hip_bf16.h>
#include <math.h>

#define NN 131072
#define BSEG 16
#define CCH 128
#define KK 16
#define EPSF 1e-9f
#define XST 136   // LDS row stride in bf16 elements (128 + 8 pad, 16B aligned)

// d_out layout (floats): out[B*K*C]=32768 | s[N*K]=2097152 | mu[B*K*2]=512 | losses[9]
#define OFF_S   32768
#define OFF_MU  2129920
#define OFF_L   2130432

// ws layout (floats):
//  [0]                       is64 flag
//  [REDC_BASE .. +64*1024)   64 staged copies of the small-reduction block:
//                            addr 0..255 sum_s[seg*16+k], 256..767 sum_pos[seg*32+2k+d], 768 ent
//  [ST_BASE .. +4*32768)     4 staged copies of out accumulator (atomics, blockIdx&3)
#define REDC_BASE 1024
#define REDC_STRIDE 1024
#define NRED 64
#define ST_BASE (REDC_BASE + NRED * REDC_STRIDE)   // 66560
#define NST 4
#define ST_SZ (BSEG * KK * CCH)                    // 32768

typedef __bf16 bf16x8 __attribute__((ext_vector_type(8)));
typedef float  f32x4  __attribute__((ext_vector_type(4)));
typedef float  f32x16 __attribute__((ext_vector_type(16)));

__device__ __forceinline__ int load_batch(const void* bptr, int n, int is64) {
    if (is64) return (int)((const long long*)bptr)[n];
    return ((const int*)bptr)[n];
}

__device__ __forceinline__ float wave_sum(float v) {
#pragma unroll
    for (int o = 32; o > 0; o >>= 1) v += __shfl_xor(v, o, 64);
    return v;
}

__device__ __forceinline__ bf16x8 pack8(float4 a, float4 b) {
    bf16x8 v;
    v[0] = (__bf16)a.x; v[1] = (__bf16)a.y; v[2] = (__bf16)a.z; v[3] = (__bf16)a.w;
    v[4] = (__bf16)b.x; v[5] = (__bf16)b.y; v[6] = (__bf16)b.z; v[7] = (__bf16)b.w;
    return v;
}

__global__ void k_zero(float* __restrict__ ws, const int* __restrict__ b32) {
    int i = blockIdx.x * 256 + threadIdx.x;   // grid 768*256 = 196608 == NRED*1024 + NST*ST_SZ
    ws[REDC_BASE + i] = 0.0f;
    if (i == 0) ws[0] = (b32[NN - 1] == 0) ? 1.0f : 0.0f;  // int64 high word at odd idx => 0
}

// R6 structure (256t, 128-node tile, grid 1024) with TWO barriers (was 3):
// GEMM1 is node-split (wave wv computes h rows [wv*32, wv*32+32), ALL 128 cols),
// so GEMM2 reads only its own wave's h rows -> barrier replaced by wave-local
// s_waitcnt lgkmcnt(0). W1 B-frags loaded from L2 per K-step (4 col-tiles).
__global__ __launch_bounds__(256, 2) void k_fused(
    const float* __restrict__ x, const void* __restrict__ batch,
    const float* __restrict__ pos, const float* __restrict__ gumbel,
    const float* __restrict__ W1, const float* __restrict__ b1,
    const float* __restrict__ W2, const float* __restrict__ b2,
    const float* __restrict__ scaling, const float* __restrict__ active_mask,
    float* __restrict__ s_out, float* __restrict__ ws)
{
    __shared__ __align__(16) __bf16 x_lds[128 * XST];
    __shared__ __align__(16) __bf16 h_lds[128 * XST];
    __shared__ __align__(16) __bf16 sT[16 * XST];
    __shared__ float2 pos_lds[128];
    __shared__ int bsegs[128];

    const int tid  = threadIdx.x;
    const int lane = tid & 63;
    const int wv   = tid >> 6;          // [0,4)
    const int n0   = blockIdx.x * 128;
    const int is64 = (int)ws[0];

    float* rc  = ws + REDC_BASE + (size_t)(blockIdx.x & (NRED - 1)) * REDC_STRIDE;
    float* stg = ws + ST_BASE   + (size_t)(blockIdx.x & (NST  - 1)) * ST_SZ;

    // ---- phase 0: stage x -> LDS bf16, batch + pos -> LDS ----
    if (tid < 128) {
        bsegs[tid] = load_batch(batch, n0 + tid, is64);
        pos_lds[tid] = ((const float2*)pos)[n0 + tid];
    }
    {
        const float4* xg = (const float4*)(x + (size_t)n0 * CCH);
#pragma unroll
        for (int i = 0; i < 8; i++) {
            int p = i * 256 + tid;          // pair of float4 = 8 elements
            float4 a = xg[2 * p], b = xg[2 * p + 1];
            *(bf16x8*)&x_lds[(p >> 4) * XST + (p & 15) * 8] = pack8(a, b);
        }
    }
    __syncthreads();

    // ========= GEMM1 (node-split): h[wv*32..+32][0..128] = relu(x @ W1^T + b1) =========
    {
        float b1j[4];
#pragma unroll
        for (int ct = 0; ct < 4; ct++) b1j[ct] = b1[ct * 32 + (lane & 31)];

        f32x16 acc[4];
#pragma unroll
        for (int ct = 0; ct < 4; ct++)
#pragma unroll
            for (int r = 0; r < 16; r++) acc[ct][r] = 0.0f;

        const int arow = wv * 32 + (lane & 31);
        const int koff = (lane >> 5) * 8;
#pragma unroll 2
        for (int ks = 0; ks < 8; ks++) {
            bf16x8 a = *(bf16x8*)&x_lds[(size_t)arow * XST + ks * 16 + koff];
#pragma unroll
            for (int ct = 0; ct < 4; ct++) {
                const float* wrow = W1 + (size_t)(ct * 32 + (lane & 31)) * CCH + ks * 16 + koff;
                float4 u = *(const float4*)wrow;
                float4 v = *(const float4*)(wrow + 4);
                acc[ct] = __builtin_amdgcn_mfma_f32_32x32x16_bf16(a, pack8(u, v), acc[ct], 0, 0, 0);
            }
        }
#pragma unroll
        for (int ct = 0; ct < 4; ct++)
#pragma unroll
            for (int r = 0; r < 16; r++) {
                int node = wv * 32 + (r & 3) + 8 * (r >> 2) + 4 * (lane >> 5);
                h_lds[(size_t)node * XST + ct * 32 + (lane & 31)] = (__bf16)fmaxf(acc[ct][r] + b1j[ct], 0.0f);
            }
    }
    // no barrier: GEMM2 below reads only this wave's own h rows. DS ops are
    // same-wave in-order; the waitcnt + sched_barrier pins compiler ordering.
    asm volatile("s_waitcnt lgkmcnt(0)" ::: "memory");
    __builtin_amdgcn_sched_barrier(0);

    // ====== fused phase: GEMM2 (16x16x32) + in-register softmax + seg sums ======
    {
        const int g  = lane >> 4;       // 0..3: node sub-group
        const int kq = lane & 15;       // this lane's k
        const int bf = bsegs[0], bl = bsegs[127];

        // prefetch gumbel[n][kq] for the 8 owned nodes (coalesced 64B per group)
        float gu[2][4];
#pragma unroll
        for (int t = 0; t < 2; t++)
#pragma unroll
            for (int r = 0; r < 4; r++) {
                int node = (wv * 2 + t) * 16 + g * 4 + r;
                gu[t][r] = gumbel[(size_t)(n0 + node) * KK + kq];
            }
        const float b2k = b2[kq];
        const float amk = active_mask[kq];
        const float sc  = scaling[0];

        f32x4 acc2[2];
#pragma unroll
        for (int t = 0; t < 2; t++)
#pragma unroll
            for (int r = 0; r < 4; r++) acc2[t][r] = 0.0f;

#pragma unroll
        for (int ks = 0; ks < 4; ks++) {
            const float* w2row = W2 + (size_t)kq * CCH + ks * 32 + g * 8;
            float4 u = *(const float4*)w2row;
            float4 v4 = *(const float4*)(w2row + 4);
            bf16x8 bwf = pack8(u, v4);
#pragma unroll
            for (int t = 0; t < 2; t++) {
                bf16x8 a = *(bf16x8*)&h_lds[(size_t)((wv * 2 + t) * 16 + kq) * XST + ks * 32 + g * 8];
                acc2[t] = __builtin_amdgcn_mfma_f32_16x16x32_bf16(a, bwf, acc2[t], 0, 0, 0);
            }
        }

        // acc2[t][r] = logits[node = (wv*2+t)*16 + g*4 + r][k = kq]
        float saccA = 0.f, pxA = 0.f, pyA = 0.f;
        float saccB = 0.f, pxB = 0.f, pyB = 0.f;
        float entacc = 0.f;
        const bool dual = (bf != bl);

#pragma unroll
        for (int t = 0; t < 2; t++) {
#pragma unroll
            for (int r = 0; r < 4; r++) {
                const int node = (wv * 2 + t) * 16 + g * 4 + r;
                float v = (acc2[t][r] + b2k) * sc;
                if (amk == 0.0f) v = -1e9f;
                v += gu[t][r];              // TAU == 1.0
                float m = v;
#pragma unroll
                for (int o = 1; o < 16; o <<= 1) m = fmaxf(m, __shfl_xor(m, o, 64));
                float e = expf(v - m);
                float ssum = e;
#pragma unroll
                for (int o = 1; o < 16; o <<= 1) ssum += __shfl_xor(ssum, o, 64);
                float s = e / ssum;

                s_out[(size_t)(n0 + node) * KK + kq] = s;
                sT[kq * XST + node] = (__bf16)s;

                float tt = s * logf(s + EPSF);
#pragma unroll
                for (int o = 1; o < 16; o <<= 1) tt += __shfl_xor(tt, o, 64);
                entacc += tt;               // replicated 16x across the group; /16 later

                const float2 pp = pos_lds[node];
                const float w0 = (bsegs[node] == bf) ? 1.0f : 0.0f;
                const float sA = s * w0;
                saccA += sA; pxA += sA * pp.x; pyA += sA * pp.y;
                if (dual) {
                    const float sB = s - sA;
                    saccB += sB; pxB += sB * pp.x; pyB += sB * pp.y;
                }
            }
        }

        // combine the 4 node-groups: lanes with same kq sum up (xor 16, 32)
        saccA += __shfl_xor(saccA, 16, 64); saccA += __shfl_xor(saccA, 32, 64);
        pxA   += __shfl_xor(pxA,   16, 64); pxA   += __shfl_xor(pxA,   32, 64);
        pyA   += __shfl_xor(pyA,   16, 64); pyA   += __shfl_xor(pyA,   32, 64);
        if (lane < 16) {
            atomicAdd(&rc[bf * 16 + lane], saccA);
            atomicAdd(&rc[256 + bf * 32 + 2 * lane],     pxA);
            atomicAdd(&rc[256 + bf * 32 + 2 * lane + 1], pyA);
        }
        if (dual) {
            saccB += __shfl_xor(saccB, 16, 64); saccB += __shfl_xor(saccB, 32, 64);
            pxB   += __shfl_xor(pxB,   16, 64); pxB   += __shfl_xor(pxB,   32, 64);
            pyB   += __shfl_xor(pyB,   16, 64); pyB   += __shfl_xor(pyB,   32, 64);
            if (lane < 16) {
                atomicAdd(&rc[bl * 16 + lane], saccB);
                atomicAdd(&rc[256 + bl * 32 + 2 * lane],     pxB);
                atomicAdd(&rc[256 + bl * 32 + 2 * lane + 1], pyB);
            }
        }
        float entw = wave_sum(entacc);
        if (lane == 0) atomicAdd(&rc[768], entw * 0.0625f);
    }
    __syncthreads();

    // ====== pooling: stg[b,k,c] += s[n,k]*x[n,c] via 16x16x32 (R0-proven) ======
    {
        const int bfirst = bsegs[0], blast = bsegs[127];
        for (int seg = bfirst; seg <= blast; seg++) {
            const bool masked = (bfirst != blast);
            f32x4 pacc[2];
#pragma unroll
            for (int t = 0; t < 2; t++)
#pragma unroll
                for (int r = 0; r < 4; r++) pacc[t][r] = 0.0f;

#pragma unroll
            for (int ks = 0; ks < 4; ks++) {
                bf16x8 a = *(bf16x8*)&sT[(size_t)(lane & 15) * XST + ks * 32 + (lane >> 4) * 8];
                if (masked) {
#pragma unroll
                    for (int i = 0; i < 8; i++) {
                        int nd = ks * 32 + (lane >> 4) * 8 + i;
                        if (bsegs[nd] != seg) a[i] = (__bf16)0.0f;
                    }
                }
#pragma unroll
                for (int t = 0; t < 2; t++) {
                    int ct = wv * 2 + t;
                    bf16x8 bx;
#pragma unroll
                    for (int i = 0; i < 8; i++)
                        bx[i] = x_lds[(size_t)(ks * 32 + (lane >> 4) * 8 + i) * XST + ct * 16 + (lane & 15)];
                    pacc[t] = __builtin_amdgcn_mfma_f32_16x16x32_bf16(a, bx, pacc[t], 0, 0, 0);
                }
            }
#pragma unroll
            for (int t = 0; t < 2; t++) {
                int c = (wv * 2 + t) * 16 + (lane & 15);
#pragma unroll
                for (int r = 0; r < 4; r++) {
                    int k = (lane >> 4) * 4 + r;
                    atomicAdd(&stg[((size_t)seg * KK + k) * CCH + c], pacc[t][r]);
                }
            }
        }
    }
}

// merged: blocks 0..31 reduce the 4 staged out-copies; block 32 computes mu + losses
__global__ __launch_bounds__(256) void k_tail(
    const float* __restrict__ ws, const float* __restrict__ active_mask,
    float* __restrict__ out, float* __restrict__ mu_out, float* __restrict__ losses)
{
    const int tid = threadIdx.x;

    if (blockIdx.x < 32) {
        int i = blockIdx.x * 256 + tid;    // [0, 8192) float4 index
        const float4* s0 = (const float4*)(ws + ST_BASE);
        const float4* s1 = (const float4*)(ws + ST_BASE + ST_SZ);
        const float4* s2 = (const float4*)(ws + ST_BASE + 2 * ST_SZ);
        const float4* s3 = (const float4*)(ws + ST_BASE + 3 * ST_SZ);
        float4 a = s0[i], b = s1[i], c = s2[i], d = s3[i];
        float4 r;
        r.x = (a.x + b.x) + (c.x + d.x);
        r.y = (a.y + b.y) + (c.y + d.y);
        r.z = (a.z + b.z) + (c.z + d.z);
        r.w = (a.w + b.w) + (c.w + d.w);
        ((float4*)out)[i] = r;
        return;
    }

    __shared__ float lsum[256];
    __shared__ float lpos[512];
    __shared__ float lent[1];
    __shared__ float smu[512];
    __shared__ float savg[16];
    __shared__ float red[256];

    // reduce the 64 staged copies: thread t owns addresses t, t+256, t+512 (769 addrs)
    for (int a = tid; a < 769; a += 256) {
        float acc = 0.0f;
#pragma unroll 8
        for (int c = 0; c < NRED; c++) acc += ws[REDC_BASE + c * REDC_STRIDE + a];
        if (a < 256) lsum[a] = acc;
        else if (a < 768) lpos[a - 256] = acc;
        else lent[0] = acc;
    }
    __syncthreads();

    if (tid < 16) {
        float a = 0.0f;
#pragma unroll
        for (int b = 0; b < 16; b++) a += lsum[b * 16 + tid];
        savg[tid] = a / (float)NN;
    }
    for (int i = tid; i < 512; i += 256) {
        int sk = i >> 1;   // b*16+k
        float v = lpos[i] / (lsum[sk] + EPSF);
        smu[i] = v;
        mu_out[i] = v;
    }
    __syncthreads();

    float rep = 0.0f;
    for (int t = tid; t < 4096; t += 256) {
        int b = t >> 8, i = (t >> 4) & 15, j = t & 15;
        if (i != j) {
            float dx = smu[b * 32 + i * 2]     - smu[b * 32 + j * 2];
            float dy = smu[b * 32 + i * 2 + 1] - smu[b * 32 + j * 2 + 1];
            rep += 1.0f / (dx * dx + dy * dy + 1.0f);
        }
    }
    red[tid] = rep;
    __syncthreads();
    for (int st = 128; st > 0; st >>= 1) {
        if (tid < st) red[tid] += red[tid + st];
        __syncthreads();
    }

    if (tid == 0) {
        const float p = 1.0f / 16.0f;
        float separation = red[0] / (float)(16 * 15);
        float entropy = -lent[0] / (float)NN;
        float diversity = 0.f, pruning = 0.f, amsum = 0.f, collapse = 0.f, mean = 0.f;
        for (int k = 0; k < 16; k++) {
            float a = savg[k];
            diversity += p * logf(p / (a + EPSF));
            pruning += fabsf(a * (1.0f - active_mask[k]));
            amsum += active_mask[k];
            collapse += (a - p) * (a - p);
            mean += a;
        }
        pruning /= 16.0f;
        mean /= 16.0f;
        float var = 0.f;
        for (int k = 0; k < 16; k++) { float d = savg[k] - mean; var += d * d; }
        float balance = sqrtf(var / 16.0f);
        float sparsity = (amsum / 16.0f) * 0.01f;
        collapse *= 2.0f;
        losses[0] = entropy;   losses[1] = diversity; losses[2] = 0.0f;
        losses[3] = pruning;   losses[4] = sparsity;  losses[5] = 0.0f;
        losses[6] = collapse;  losses[7] = balance;   losses[8] = separation;
    }
}

extern "C" void kernel_launch(void* const* d_in, const int* in_sizes, int n_in,
                              void* d_out, int out_size, void* d_ws, size_t ws_size,
                              hipStream_t stream) {
    const float* x       = (const float*)d_in[0];
    const void*  batch   = d_in[1];
    const float* pos     = (const float*)d_in[2];
    const float* gumbel  = (const float*)d_in[3];
    const float* W1      = (const float*)d_in[4];
    const float* b1      = (const float*)d_in[5];
    const float* W2      = (const float*)d_in[6];
    const float* b2      = (const float*)d_in[7];
    const float* scaling = (const float*)d_in[8];
    const float* am      = (const float*)d_in[9];

    float* out      = (float*)d_out;
    float* s_sec    = out + OFF_S;
    float* mu_sec   = out + OFF_MU;
    float* loss_sec = out + OFF_L;
    float* wsf      = (float*)d_ws;

    k_zero<<<768, 256, 0, stream>>>(wsf, (const int*)batch);
    k_fused<<<NN / 128, 256, 0, stream>>>(x, batch, pos, gumbel, W1, b1, W2, b2,
                                          scaling, am, s_sec, wsf);
    k_tail<<<33, 256, 0, stream>>>(wsf, am, out, mu_sec, loss_sec);
}

// Round 8
// 155.140 us; speedup vs baseline: 1.1521x; 1.1521x over previous
//
#include <hip/hip_runtime.h>
#include <hip/hip_bf16.h>
#include <math.h>

#define NN 131072
#define BSEG 16
#define CCH 128
#define KK 16
#define EPSF 1e-9f
#define XST 136   // LDS row stride in bf16 elements (128 + 8 pad, 16B aligned)

// d_out layout (floats): out[B*K*C]=32768 | s[N*K]=2097152 | mu[B*K*2]=512 | losses[9]
#define OFF_S   32768
#define OFF_MU  2129920
#define OFF_L   2130432

// ws layout (floats):
//  [0]                       is64 flag
//  [REDC_BASE .. +64*1024)   64 staged copies of the small-reduction block:
//                            addr 0..255 sum_s[seg*16+k], 256..767 sum_pos[seg*32+2k+d], 768 ent
//  [ST_BASE .. +4*32768)     4 staged copies of out accumulator (atomics, blockIdx&3)
#define REDC_BASE 1024
#define REDC_STRIDE 1024
#define NRED 64
#define ST_BASE (REDC_BASE + NRED * REDC_STRIDE)   // 66560
#define NST 4
#define ST_SZ (BSEG * KK * CCH)                    // 32768

#define TILES 2   // 128-node tiles per block; pooling acc carried in regs across tiles

typedef __bf16 bf16x8 __attribute__((ext_vector_type(8)));
typedef float  f32x4  __attribute__((ext_vector_type(4)));
typedef float  f32x16 __attribute__((ext_vector_type(16)));

__device__ __forceinline__ int load_batch(const void* bptr, int n, int is64) {
    if (is64) return (int)((const long long*)bptr)[n];
    return ((const int*)bptr)[n];
}

__device__ __forceinline__ float wave_sum(float v) {
#pragma unroll
    for (int o = 32; o > 0; o >>= 1) v += __shfl_xor(v, o, 64);
    return v;
}

__device__ __forceinline__ bf16x8 pack8(float4 a, float4 b) {
    bf16x8 v;
    v[0] = (__bf16)a.x; v[1] = (__bf16)a.y; v[2] = (__bf16)a.z; v[3] = (__bf16)a.w;
    v[4] = (__bf16)b.x; v[5] = (__bf16)b.y; v[6] = (__bf16)b.z; v[7] = (__bf16)b.w;
    return v;
}

__global__ void k_zero(float* __restrict__ ws, const int* __restrict__ b32) {
    int i = blockIdx.x * 256 + threadIdx.x;   // grid 768*256 = 196608 == NRED*1024 + NST*ST_SZ
    ws[REDC_BASE + i] = 0.0f;
    if (i == 0) ws[0] = (b32[NN - 1] == 0) ? 1.0f : 0.0f;  // int64 high word at odd idx => 0
}

// R6 structure (proven 43us: 256t, col-split GEMM1 with register-hoisted W1,
// fused GEMM2+softmax, 3 barriers/tile) + TILES=2: two 128-node tiles per block,
// pooling accumulator carried in registers across tiles (R5-proven curseg logic)
// -> stg atomics halved (2.1M -> ~1.05M). W1 frags load once per block at entry
// (overlaps tile-0 staging); gumbel prefetched during each tile's staging phase.
// Grid 512 = exactly 2 blocks/CU resident, single dispatch round.
// R7 lesson: do NOT trade the hoisted-W1 register operand for a removed barrier.
__global__ __launch_bounds__(256, 2) void k_fused(
    const float* __restrict__ x, const void* __restrict__ batch,
    const float* __restrict__ pos, const float* __restrict__ gumbel,
    const float* __restrict__ W1, const float* __restrict__ b1,
    const float* __restrict__ W2, const float* __restrict__ b2,
    const float* __restrict__ scaling, const float* __restrict__ active_mask,
    float* __restrict__ s_out, float* __restrict__ ws)
{
    __shared__ __align__(16) __bf16 x_lds[128 * XST];
    __shared__ __align__(16) __bf16 h_lds[128 * XST];
    __shared__ __align__(16) __bf16 sT[16 * XST];
    __shared__ float2 pos_lds[128];
    __shared__ int bsegs[128];

    const int tid  = threadIdx.x;
    const int lane = tid & 63;
    const int wv   = tid >> 6;          // [0,4)
    const int is64 = (int)ws[0];

    float* rc  = ws + REDC_BASE + (size_t)(blockIdx.x & (NRED - 1)) * REDC_STRIDE;
    float* stg = ws + ST_BASE   + (size_t)(blockIdx.x & (NST  - 1)) * ST_SZ;

    // ---- W1 fragment + bias, loaded ONCE per block (issues overlap tile-0 staging) ----
    bf16x8 bfr[8];
    {
        const float* wrow = W1 + (size_t)(wv * 32 + (lane & 31)) * CCH + (lane >> 5) * 8;
#pragma unroll
        for (int ks = 0; ks < 8; ks++) {
            float4 u = *(const float4*)(wrow + ks * 16);
            float4 v = *(const float4*)(wrow + ks * 16 + 4);
            bfr[ks] = pack8(u, v);
        }
    }
    const float b1j = b1[wv * 32 + (lane & 31)];

    // pooling accumulator carried ACROSS tiles (batch sorted => seg rarely changes)
    f32x4 pacc[2];
#pragma unroll
    for (int t = 0; t < 2; t++)
#pragma unroll
        for (int r = 0; r < 4; r++) pacc[t][r] = 0.0f;
    int curseg = -1;

    for (int t = 0; t < TILES; t++) {
        const int n0 = blockIdx.x * (TILES * 128) + t * 128;

        if (t) __syncthreads();   // previous tile's pooling must finish reading x_lds/sT/bsegs

        // ---- stage: batch+pos -> LDS, gumbel -> regs, x -> LDS bf16 ----
        if (tid < 128) {
            bsegs[tid] = load_batch(batch, n0 + tid, is64);
            pos_lds[tid] = ((const float2*)pos)[n0 + tid];
        }
        // prefetch gumbel[n][kq] for the 8 nodes this lane owns in the fused phase
        float gu[2][4];
        {
            const int g  = lane >> 4;
            const int kq = lane & 15;
#pragma unroll
            for (int tt = 0; tt < 2; tt++)
#pragma unroll
                for (int r = 0; r < 4; r++) {
                    int node = (wv * 2 + tt) * 16 + g * 4 + r;
                    gu[tt][r] = gumbel[(size_t)(n0 + node) * KK + kq];
                }
        }
        {
            const float4* xg = (const float4*)(x + (size_t)n0 * CCH);
#pragma unroll
            for (int i = 0; i < 8; i++) {
                int p = i * 256 + tid;          // pair of float4 = 8 elements
                float4 a = xg[2 * p], b = xg[2 * p + 1];
                *(bf16x8*)&x_lds[(p >> 4) * XST + (p & 15) * 8] = pack8(a, b);
            }
        }
        __syncthreads();

        // ================= GEMM1: h = relu(x @ W1^T + b1), 32x32x16 =================
        {
            f32x16 acc[4];
#pragma unroll
            for (int mt = 0; mt < 4; mt++)
#pragma unroll
                for (int r = 0; r < 16; r++) acc[mt][r] = 0.0f;

#pragma unroll
            for (int ks = 0; ks < 8; ks++) {
#pragma unroll
                for (int mt = 0; mt < 4; mt++) {
                    bf16x8 a = *(bf16x8*)&x_lds[(size_t)(mt * 32 + (lane & 31)) * XST + ks * 16 + (lane >> 5) * 8];
                    acc[mt] = __builtin_amdgcn_mfma_f32_32x32x16_bf16(a, bfr[ks], acc[mt], 0, 0, 0);
                }
            }
#pragma unroll
            for (int mt = 0; mt < 4; mt++)
#pragma unroll
                for (int r = 0; r < 16; r++) {
                    int node = mt * 32 + (r & 3) + 8 * (r >> 2) + 4 * (lane >> 5);
                    h_lds[(size_t)node * XST + wv * 32 + (lane & 31)] = (__bf16)fmaxf(acc[mt][r] + b1j, 0.0f);
                }
        }
        __syncthreads();

        // ====== fused phase: GEMM2 (16x16x32) + in-register softmax + seg sums ======
        {
            const int g  = lane >> 4;       // 0..3: node sub-group
            const int kq = lane & 15;       // this lane's k
            const int bf = bsegs[0], bl = bsegs[127];

            const float b2k = b2[kq];
            const float amk = active_mask[kq];
            const float sc  = scaling[0];

            f32x4 acc2[2];
#pragma unroll
            for (int tt = 0; tt < 2; tt++)
#pragma unroll
                for (int r = 0; r < 4; r++) acc2[tt][r] = 0.0f;

#pragma unroll
            for (int ks = 0; ks < 4; ks++) {
                const float* w2row = W2 + (size_t)kq * CCH + ks * 32 + g * 8;
                float4 u = *(const float4*)w2row;
                float4 v4 = *(const float4*)(w2row + 4);
                bf16x8 bwf = pack8(u, v4);
#pragma unroll
                for (int tt = 0; tt < 2; tt++) {
                    bf16x8 a = *(bf16x8*)&h_lds[(size_t)((wv * 2 + tt) * 16 + kq) * XST + ks * 32 + g * 8];
                    acc2[tt] = __builtin_amdgcn_mfma_f32_16x16x32_bf16(a, bwf, acc2[tt], 0, 0, 0);
                }
            }

            // acc2[tt][r] = logits[node = (wv*2+tt)*16 + g*4 + r][k = kq]
            float saccA = 0.f, pxA = 0.f, pyA = 0.f;
            float saccB = 0.f, pxB = 0.f, pyB = 0.f;
            float entacc = 0.f;
            const bool dual = (bf != bl);

#pragma unroll
            for (int tt = 0; tt < 2; tt++) {
#pragma unroll
                for (int r = 0; r < 4; r++) {
                    const int node = (wv * 2 + tt) * 16 + g * 4 + r;
                    float v = (acc2[tt][r] + b2k) * sc;
                    if (amk == 0.0f) v = -1e9f;
                    v += gu[tt][r];             // TAU == 1.0
                    float m = v;
#pragma unroll
                    for (int o = 1; o < 16; o <<= 1) m = fmaxf(m, __shfl_xor(m, o, 64));
                    float e = expf(v - m);
                    float ssum = e;
#pragma unroll
                    for (int o = 1; o < 16; o <<= 1) ssum += __shfl_xor(ssum, o, 64);
                    float s = e / ssum;

                    s_out[(size_t)(n0 + node) * KK + kq] = s;
                    sT[kq * XST + node] = (__bf16)s;

                    float te = s * logf(s + EPSF);
#pragma unroll
                    for (int o = 1; o < 16; o <<= 1) te += __shfl_xor(te, o, 64);
                    entacc += te;               // replicated 16x across the group; /16 later

                    const float2 pp = pos_lds[node];
                    const float w0 = (bsegs[node] == bf) ? 1.0f : 0.0f;
                    const float sA = s * w0;
                    saccA += sA; pxA += sA * pp.x; pyA += sA * pp.y;
                    if (dual) {
                        const float sB = s - sA;
                        saccB += sB; pxB += sB * pp.x; pyB += sB * pp.y;
                    }
                }
            }

            // combine the 4 node-groups: lanes with same kq sum up (xor 16, 32)
            saccA += __shfl_xor(saccA, 16, 64); saccA += __shfl_xor(saccA, 32, 64);
            pxA   += __shfl_xor(pxA,   16, 64); pxA   += __shfl_xor(pxA,   32, 64);
            pyA   += __shfl_xor(pyA,   16, 64); pyA   += __shfl_xor(pyA,   32, 64);
            if (lane < 16) {
                atomicAdd(&rc[bf * 16 + lane], saccA);
                atomicAdd(&rc[256 + bf * 32 + 2 * lane],     pxA);
                atomicAdd(&rc[256 + bf * 32 + 2 * lane + 1], pyA);
            }
            if (dual) {
                saccB += __shfl_xor(saccB, 16, 64); saccB += __shfl_xor(saccB, 32, 64);
                pxB   += __shfl_xor(pxB,   16, 64); pxB   += __shfl_xor(pxB,   32, 64);
                pyB   += __shfl_xor(pyB,   16, 64); pyB   += __shfl_xor(pyB,   32, 64);
                if (lane < 16) {
                    atomicAdd(&rc[bl * 16 + lane], saccB);
                    atomicAdd(&rc[256 + bl * 32 + 2 * lane],     pxB);
                    atomicAdd(&rc[256 + bl * 32 + 2 * lane + 1], pyB);
                }
            }
            float entw = wave_sum(entacc);
            if (lane == 0) atomicAdd(&rc[768], entw * 0.0625f);
        }
        __syncthreads();

        // == pooling: pacc[tt][k,c] += s[n,k]*x[n,c] via 16x16x32; flush on seg change ==
        {
            const int bf = bsegs[0], bl = bsegs[127];
            const bool masked = (bf != bl);
            for (int seg = bf; seg <= bl; seg++) {
                if (seg != curseg) {
                    if (curseg >= 0) {
#pragma unroll
                        for (int tt = 0; tt < 2; tt++) {
#pragma unroll
                            for (int r = 0; r < 4; r++) {
                                int k = (lane >> 4) * 4 + r;
                                int c = (wv * 2 + tt) * 16 + (lane & 15);
                                atomicAdd(&stg[((size_t)curseg * KK + k) * CCH + c], pacc[tt][r]);
                            }
#pragma unroll
                            for (int r = 0; r < 4; r++) pacc[tt][r] = 0.0f;
                        }
                    }
                    curseg = seg;
                }
#pragma unroll
                for (int ks = 0; ks < 4; ks++) {
                    bf16x8 a = *(bf16x8*)&sT[(size_t)(lane & 15) * XST + ks * 32 + (lane >> 4) * 8];
                    if (masked) {
#pragma unroll
                        for (int i = 0; i < 8; i++) {
                            int nd = ks * 32 + (lane >> 4) * 8 + i;
                            if (bsegs[nd] != seg) a[i] = (__bf16)0.0f;
                        }
                    }
#pragma unroll
                    for (int tt = 0; tt < 2; tt++) {
                        int ct = wv * 2 + tt;
                        bf16x8 bx;
#pragma unroll
                        for (int i = 0; i < 8; i++)
                            bx[i] = x_lds[(size_t)(ks * 32 + (lane >> 4) * 8 + i) * XST + ct * 16 + (lane & 15)];
                        pacc[tt] = __builtin_amdgcn_mfma_f32_16x16x32_bf16(a, bx, pacc[tt], 0, 0, 0);
                    }
                }
            }
        }
    }

    // final flush of the register pooling accumulator
    if (curseg >= 0) {
#pragma unroll
        for (int tt = 0; tt < 2; tt++) {
#pragma unroll
            for (int r = 0; r < 4; r++) {
                int k = (lane >> 4) * 4 + r;
                int c = (wv * 2 + tt) * 16 + (lane & 15);
                atomicAdd(&stg[((size_t)curseg * KK + k) * CCH + c], pacc[tt][r]);
            }
        }
    }
}

// merged: blocks 0..31 reduce the 4 staged out-copies; block 32 computes mu + losses
__global__ __launch_bounds__(256) void k_tail(
    const float* __restrict__ ws, const float* __restrict__ active_mask,
    float* __restrict__ out, float* __restrict__ mu_out, float* __restrict__ losses)
{
    const int tid = threadIdx.x;

    if (blockIdx.x < 32) {
        int i = blockIdx.x * 256 + tid;    // [0, 8192) float4 index
        const float4* s0 = (const float4*)(ws + ST_BASE);
        const float4* s1 = (const float4*)(ws + ST_BASE + ST_SZ);
        const float4* s2 = (const float4*)(ws + ST_BASE + 2 * ST_SZ);
        const float4* s3 = (const float4*)(ws + ST_BASE + 3 * ST_SZ);
        float4 a = s0[i], b = s1[i], c = s2[i], d = s3[i];
        float4 r;
        r.x = (a.x + b.x) + (c.x + d.x);
        r.y = (a.y + b.y) + (c.y + d.y);
        r.z = (a.z + b.z) + (c.z + d.z);
        r.w = (a.w + b.w) + (c.w + d.w);
        ((float4*)out)[i] = r;
        return;
    }

    __shared__ float lsum[256];
    __shared__ float lpos[512];
    __shared__ float lent[1];
    __shared__ float smu[512];
    __shared__ float savg[16];
    __shared__ float red[256];

    // reduce the 64 staged copies: thread t owns addresses t, t+256, t+512 (769 addrs)
    for (int a = tid; a < 769; a += 256) {
        float acc = 0.0f;
#pragma unroll 8
        for (int c = 0; c < NRED; c++) acc += ws[REDC_BASE + c * REDC_STRIDE + a];
        if (a < 256) lsum[a] = acc;
        else if (a < 768) lpos[a - 256] = acc;
        else lent[0] = acc;
    }
    __syncthreads();

    if (tid < 16) {
        float a = 0.0f;
#pragma unroll
        for (int b = 0; b < 16; b++) a += lsum[b * 16 + tid];
        savg[tid] = a / (float)NN;
    }
    for (int i = tid; i < 512; i += 256) {
        int sk = i >> 1;   // b*16+k
        float v = lpos[i] / (lsum[sk] + EPSF);
        smu[i] = v;
        mu_out[i] = v;
    }
    __syncthreads();

    float rep = 0.0f;
    for (int t = tid; t < 4096; t += 256) {
        int b = t >> 8, i = (t >> 4) & 15, j = t & 15;
        if (i != j) {
            float dx = smu[b * 32 + i * 2]     - smu[b * 32 + j * 2];
            float dy = smu[b * 32 + i * 2 + 1] - smu[b * 32 + j * 2 + 1];
            rep += 1.0f / (dx * dx + dy * dy + 1.0f);
        }
    }
    red[tid] = rep;
    __syncthreads();
    for (int st = 128; st > 0; st >>= 1) {
        if (tid < st) red[tid] += red[tid + st];
        __syncthreads();
    }

    if (tid == 0) {
        const float p = 1.0f / 16.0f;
        float separation = red[0] / (float)(16 * 15);
        float entropy = -lent[0] / (float)NN;
        float diversity = 0.f, pruning = 0.f, amsum = 0.f, collapse = 0.f, mean = 0.f;
        for (int k = 0; k < 16; k++) {
            float a = savg[k];
            diversity += p * logf(p / (a + EPSF));
            pruning += fabsf(a * (1.0f - active_mask[k]));
            amsum += active_mask[k];
            collapse += (a - p) * (a - p);
            mean += a;
        }
        pruning /= 16.0f;
        mean /= 16.0f;
        float var = 0.f;
        for (int k = 0; k < 16; k++) { float d = savg[k] - mean; var += d * d; }
        float balance = sqrtf(var / 16.0f);
        float sparsity = (amsum / 16.0f) * 0.01f;
        collapse *= 2.0f;
        losses[0] = entropy;   losses[1] = diversity; losses[2] = 0.0f;
        losses[3] = pruning;   losses[4] = sparsity;  losses[5] = 0.0f;
        losses[6] = collapse;  losses[7] = balance;   losses[8] = separation;
    }
}

extern "C" void kernel_launch(void* const* d_in, const int* in_sizes, int n_in,
                              void* d_out, int out_size, void* d_ws, size_t ws_size,
                              hipStream_t stream) {
    const float* x       = (const float*)d_in[0];
    const void*  batch   = d_in[1];
    const float* pos     = (const float*)d_in[2];
    const float* gumbel  = (const float*)d_in[3];
    const float* W1      = (const float*)d_in[4];
    const float* b1      = (const float*)d_in[5];
    const float* W2      = (const float*)d_in[6];
    const float* b2      = (const float*)d_in[7];
    const float* scaling = (const float*)d_in[8];
    const float* am      = (const float*)d_in[9];

    float* out      = (float*)d_out;
    float* s_sec    = out + OFF_S;
    float* mu_sec   = out + OFF_MU;
    float* loss_sec = out + OFF_L;
    float* wsf      = (float*)d_ws;

    k_zero<<<768, 256, 0, stream>>>(wsf, (const int*)batch);
    k_fused<<<NN / 256, 256, 0, stream>>>(x, batch, pos, gumbel, W1, b1, W2, b2,
                                          scaling, am, s_sec, wsf);
    k_tail<<<33, 256, 0, stream>>>(wsf, am, out, mu_sec, loss_sec);
}